// Round 16
// baseline (284.123 us; speedup 1.0000x reference)
//
#include <hip/hip_runtime.h>
#include <math.h>
#include <float.h>

#define GRIDP 112
#define NPIX (GRIDP * GRIDP)   // 12544
#define D 16
#define TSA 3328               // A-buf bytes/vertex-tile: 3 planes*1024 + v2 128B + pad
#define TSB 3072               // B-buf bytes/pixel-tile:  3 planes*1024
#define G 2                    // pixel tiles per wave
#define TG 2                   // vertex tiles per staged group
#define GRPB (TG * TSA)        // 6656 bytes
#define GRPB_PAD 7168          // staged as 7 x 1024B wave-issues (512B overrun into pad)
#define NISS 7

typedef short s16x8 __attribute__((ext_vector_type(8)));
typedef float f32x16 __attribute__((ext_vector_type(16)));
typedef unsigned int uint32;
typedef unsigned long long u64;
typedef const __attribute__((address_space(1))) uint32* gas_ptr;
typedef __attribute__((address_space(3))) uint32* las_ptr;

__device__ inline unsigned short f2bf(float x) {      // RTNE float->bf16 bits
    unsigned u = __float_as_uint(x);
    u += 0x7fffu + ((u >> 16) & 1u);
    return (unsigned short)(u >> 16);
}
__device__ inline float bf2f(unsigned short b) { return __uint_as_float(((unsigned)b) << 16); }

#define MFMA __builtin_amdgcn_mfma_f32_32x32x16_bf16

// monotone f32 -> u32 map (a<b => map(a)<map(b)); equal floats map equal
__device__ inline unsigned fmap(float f) {
    unsigned b = __float_as_uint(f);
    return (b & 0x80000000u) ? ~b : (b | 0x80000000u);
}

// split one row of 16 floats into 3 bf16 planes, 16B vector stores
__device__ __forceinline__ void split_store_row(const float* x, char* base, int row) {
    unsigned short t0[D], t1[D], t2[D];
#pragma unroll
    for (int e = 0; e < D; ++e) {
        float v = x[e];
        unsigned short a = f2bf(v);  float r1 = v - bf2f(a);
        unsigned short b = f2bf(r1); float r2 = r1 - bf2f(b);
        t0[e] = a; t1[e] = b; t2[e] = f2bf(r2);
    }
#pragma unroll
    for (int h2 = 0; h2 < 2; ++h2) {
        char* p = base + h2 * 512 + row * 16;
        s16x8 v0, v1, v2s;
#pragma unroll
        for (int j = 0; j < 8; ++j) {
            v0[j] = (short)t0[h2 * 8 + j];
            v1[j] = (short)t1[h2 * 8 + j];
            v2s[j] = (short)t2[h2 * 8 + j];
        }
        *(s16x8*)(p)        = v0;
        *(s16x8*)(p + 1024) = v1;
        *(s16x8*)(p + 2048) = v2s;
    }
}

// ---- fused prep: [verts | pixels | feats-copy | key-init] segments ----
__global__ __launch_bounds__(256) void prep_fused(
    const float* __restrict__ verts, const float* __restrict__ feats,
    char* __restrict__ abuf, char* __restrict__ bbuf,
    float* __restrict__ v2p, float* __restrict__ outf, u64* __restrict__ keys,
    int M, int Mtiles, int NP, int PTiles, int nvb, int npb, int ncb, int nf4)
{
    int bx = blockIdx.x;
    if (bx < nvb) {
        int mp = bx * 256 + threadIdx.x;
        if (mp >= Mtiles * 32) return;
        int tile = mp >> 5, row = mp & 31;
        float x[D]; float v2;
        if (mp < M) {
            const float4* r4 = (const float4*)(verts + (size_t)mp * D);
            float4 a = r4[0], b = r4[1], c = r4[2], d = r4[3];
            x[0]=a.x; x[1]=a.y; x[2]=a.z; x[3]=a.w;
            x[4]=b.x; x[5]=b.y; x[6]=b.z; x[7]=b.w;
            x[8]=c.x; x[9]=c.y; x[10]=c.z; x[11]=c.w;
            x[12]=d.x; x[13]=d.y; x[14]=d.z; x[15]=d.w;
            float s = 0.f;
#pragma unroll
            for (int e = 0; e < D; ++e) s = fmaf(x[e], x[e], s);
            v2 = s;
            v2p[mp] = s;
        } else {
#pragma unroll
            for (int e = 0; e < D; ++e) x[e] = 0.f;
            v2 = FLT_MAX;   // pad rows never win
        }
        size_t tb = (size_t)tile * TSA;
        int hv = (row >> 2) & 1, rv = (row & 3) + 4 * (row >> 3);
        *(float*)(abuf + tb + 3072 + hv * 64 + rv * 4) = v2;
        split_store_row(x, abuf + tb, row);
    } else if (bx < nvb + npb) {
        int p = (bx - nvb) * 256 + threadIdx.x;
        if (p >= PTiles * 32) return;
        int tile = p >> 5, colr = p & 31;
        float x[D];
        if (p < NP) {
            int b = p / NPIX, n = p - b * NPIX;
            const float* xf = feats + ((size_t)b * D) * NPIX + n;
#pragma unroll
            for (int e = 0; e < D; ++e) x[e] = -2.0f * xf[(size_t)e * NPIX];
        } else {
#pragma unroll
            for (int e = 0; e < D; ++e) x[e] = 0.f;
        }
        split_store_row(x, bbuf + (size_t)tile * TSB, colr);
    } else if (bx < nvb + npb + ncb) {
        int i = (bx - nvb - npb) * 256 + threadIdx.x;     // float4 index
        if (i < nf4)
            ((float4*)outf)[i] = ((const float4*)feats)[i];
    } else {
        int i = (bx - nvb - npb - ncb) * 256 + threadIdx.x;
        if (i < NP) keys[i] = ~0ull;                      // re-init every launch
    }
}

__device__ inline float mintree16(const f32x16& a) {
    float a0 = fminf(fminf(a[0],  a[1]),  a[2]);   // v_min3 tree
    float a1 = fminf(fminf(a[3],  a[4]),  a[5]);
    float a2 = fminf(fminf(a[6],  a[7]),  a[8]);
    float a3 = fminf(fminf(a[9],  a[10]), a[11]);
    float a4 = fminf(fminf(a[12], a[13]), a[14]);
    float a5 = fminf(fminf(a0, a1), a[15]);
    float a6 = fminf(fminf(a2, a3), a4);
    return fminf(a5, a6);
}

// stage one TG-tile group (7 x 1024B wave-issues incl. 512B pad) into LDS
__device__ __forceinline__ void stage_group(const char* gbase, char* lbase,
                                            int wid, int lane) {
    for (int i = wid; i < NISS; i += 4) {
        __builtin_amdgcn_global_load_lds(
            (gas_ptr)(gbase + i * 1024 + lane * 16),
            (las_ptr)(lbase + i * 1024),
            16, 0, 0);
    }
}

struct AFrag { s16x8 ah, am, al; f32x16 c; };

__device__ __forceinline__ AFrag load_frag(const char* lt, int h, int col) {
    AFrag f;
    f.ah = *(const s16x8*)(lt + (size_t)h * 512 + (size_t)col * 16);
    f.am = *(const s16x8*)(lt + 1024 + (size_t)h * 512 + (size_t)col * 16);
    f.al = *(const s16x8*)(lt + 2048 + (size_t)h * 512 + (size_t)col * 16);
    f.c  = *(const f32x16*)(lt + 3072 + (size_t)h * 64);   // broadcast
    return f;
}

// keep an MFMA chain / ds_read live without consuming it (ablation sinks)
__device__ __forceinline__ void sink_acc(const f32x16* acc) {
#pragma unroll
    for (int g = 0; g < G; ++g)
        asm volatile("" :: "v"(acc[g][0]), "v"(acc[g][15]));
}
__device__ __forceinline__ void sink_frag(const AFrag& f) {
    asm volatile("" :: "v"((int)f.ah[0]), "v"((int)f.am[0]),
                        "v"((int)f.al[0]), "v"(f.c[0]));
}

__device__ __forceinline__ void chain_mfma(
    const AFrag& f, const s16x8* bh, const s16x8* bm, const s16x8* bl,
    f32x16* acc)
{
#pragma unroll
    for (int g = 0; g < G; ++g) acc[g] = MFMA(f.ah, bh[g], f.c, 0, 0, 0);
#pragma unroll
    for (int g = 0; g < G; ++g) acc[g] = MFMA(f.ah, bm[g], acc[g], 0, 0, 0);
#pragma unroll
    for (int g = 0; g < G; ++g) acc[g] = MFMA(f.am, bh[g], acc[g], 0, 0, 0);
#pragma unroll
    for (int g = 0; g < G; ++g) acc[g] = MFMA(f.ah, bl[g], acc[g], 0, 0, 0);
#pragma unroll
    for (int g = 0; g < G; ++g) acc[g] = MFMA(f.am, bm[g], acc[g], 0, 0, 0);
#pragma unroll
    for (int g = 0; g < G; ++g) acc[g] = MFMA(f.al, bh[g], acc[g], 0, 0, 0);
}

__device__ __forceinline__ void tree_upd(
    const f32x16* acc, int mt, float* best, int* btl)
{
#pragma unroll
    for (int g = 0; g < G; ++g) {
        float m = mintree16(acc[g]);
        if (m < best[g]) { btl[g] = mt; best[g] = m; }   // strict <: earliest tile
    }
}

// ---- ablation scan. V=0 full (real output); V=1 MFMA-only (no trees);
// V=2 trees + 1 MFMA per g (1/6 matrix work). V1/V2 write nothing. ----
template<int V>
__global__ __launch_bounds__(256) void scan_v(
    const char* __restrict__ abuf, const char* __restrict__ bbuf,
    u64* __restrict__ keys, int Mtiles, int chunk, int NP, int PTiles)
{
    __shared__ __align__(16) char smem[2][GRPB_PAD];
    int lane = threadIdx.x & 63;
    int wid  = threadIdx.x >> 6;
    int col  = lane & 31, h = lane >> 5;
    int ptb  = (blockIdx.x * 4 + wid) * G;      // no early return: barriers below

    s16x8 bh[G], bm[G], bl[G];
#pragma unroll
    for (int g = 0; g < G; ++g) {
        int pt = ptb + g;
        int ptc = pt < PTiles ? pt : PTiles - 1;
        const char* bb = bbuf + (size_t)ptc * TSB + (size_t)h * 512 + (size_t)col * 16;
        bh[g] = *(const s16x8*)bb;
        bm[g] = *(const s16x8*)(bb + 1024);
        bl[g] = *(const s16x8*)(bb + 2048);
    }

    int mt0 = blockIdx.y * chunk;
    int mt1 = mt0 + chunk; if (mt1 > Mtiles) mt1 = Mtiles;
    int nT   = mt1 - mt0;
    int nGrp = (nT + TG - 1) / TG;

    float best[G]; int btl[G];
#pragma unroll
    for (int g = 0; g < G; ++g) { best[g] = FLT_MAX; btl[g] = mt0; }

    const char* gsrc = abuf + (size_t)mt0 * TSA;

    stage_group(gsrc, smem[0], wid, lane);
    __syncthreads();

    int cur = 0;
    for (int grp = 0; grp < nGrp; ++grp) {
        if (grp + 1 < nGrp)
            stage_group(gsrc + (size_t)(grp + 1) * GRPB, smem[cur ^ 1], wid, lane);

        const char* lb = smem[cur];
        int mtb = mt0 + grp * TG;
        int rem = nT - grp * TG;
        if (rem >= 2) {
            AFrag f0 = load_frag(lb, h, col);
            AFrag f1 = load_frag(lb + TSA, h, col);
            if constexpr (V == 0) {
                f32x16 a0[G], a1[G];
                chain_mfma(f0, bh, bm, bl, a0);
                chain_mfma(f1, bh, bm, bl, a1);
                tree_upd(a0, mtb,     best, btl);
                tree_upd(a1, mtb + 1, best, btl);
            } else if constexpr (V == 1) {          // no trees: MFMA+LDS+stage only
                f32x16 a0[G], a1[G];
                chain_mfma(f0, bh, bm, bl, a0);
                chain_mfma(f1, bh, bm, bl, a1);
                sink_acc(a0); sink_acc(a1);
            } else {                                 // V==2: 1 MFMA per g + trees
                sink_frag(f0); sink_frag(f1);
                f32x16 a0[G], a1[G];
#pragma unroll
                for (int g = 0; g < G; ++g) a0[g] = MFMA(f0.ah, bh[g], f0.c, 0, 0, 0);
#pragma unroll
                for (int g = 0; g < G; ++g) a1[g] = MFMA(f1.ah, bh[g], f1.c, 0, 0, 0);
                tree_upd(a0, mtb,     best, btl);
                tree_upd(a1, mtb + 1, best, btl);
            }
        } else {
            AFrag f0 = load_frag(lb, h, col);
            if constexpr (V == 0) {
                f32x16 a0[G];
                chain_mfma(f0, bh, bm, bl, a0);
                tree_upd(a0, mtb, best, btl);
            } else if constexpr (V == 1) {
                f32x16 a0[G];
                chain_mfma(f0, bh, bm, bl, a0);
                sink_acc(a0);
            } else {
                sink_frag(f0);
                f32x16 a0[G];
#pragma unroll
                for (int g = 0; g < G; ++g) a0[g] = MFMA(f0.ah, bh[g], f0.c, 0, 0, 0);
                tree_upd(a0, mtb, best, btl);
            }
        }
        __syncthreads();    // drains stage (vmcnt) + protects buffer reuse
        cur ^= 1;
    }

    if constexpr (V == 0) {
        // merge halves (equal value -> smaller tile), then one atomicMin per pixel
#pragma unroll
        for (int g = 0; g < G; ++g) {
            float o = __shfl_xor(best[g], 32, 64);
            int  ot = __shfl_xor(btl[g], 32, 64);
            if (o < best[g] || (o == best[g] && ot < btl[g])) { best[g] = o; btl[g] = ot; }
        }
        if (lane < 32) {
#pragma unroll
            for (int g = 0; g < G; ++g) {
                int pt = ptb + g;
                int px = pt * 32 + col;
                if (pt < PTiles && px < NP) {
                    u64 key = ((u64)fmap(best[g]) << 32) | (unsigned)btl[g];
                    atomicMin(&keys[px], key);   // min value, tie -> smaller tile
                }
            }
        }
    } else {
        // keep the best/btl chains live without any memory side effect
#pragma unroll
        for (int g = 0; g < G; ++g)
            asm volatile("" :: "v"(best[g]), "v"((float)btl[g]));
    }
}

// ---- finalize: unpack winning tile, exact fp32 argmin inside it ----
__global__ __launch_bounds__(256) void finalize(
    const u64* __restrict__ keys,
    const float* __restrict__ feats, const float* __restrict__ verts,
    const float* __restrict__ v2p, float* __restrict__ dps,
    int NP, int M)
{
    int p = blockIdx.x * 256 + threadIdx.x;
    if (p >= NP) return;
    int bt = (int)(unsigned)(keys[p] & 0xffffffffu);
    int b = p / NPIX, n = p - b * NPIX;
    const float* xf = feats + ((size_t)b * D) * NPIX + n;
    float xs[D];
#pragma unroll
    for (int d2 = 0; d2 < D; ++d2) xs[d2] = -2.0f * xf[(size_t)d2 * NPIX];
    int m0 = bt * 32, m1 = m0 + 32; if (m1 > M) m1 = M;
    float best = FLT_MAX; int bi = m0;
    for (int m = m0; m < m1; ++m) {
        const float4* vr = (const float4*)(verts + (size_t)m * D);
        float4 a = vr[0], bq = vr[1], c = vr[2], d = vr[3];
        float acc = v2p[m];
        acc = fmaf(a.x, xs[0], acc);  acc = fmaf(a.y, xs[1], acc);
        acc = fmaf(a.z, xs[2], acc);  acc = fmaf(a.w, xs[3], acc);
        acc = fmaf(bq.x, xs[4], acc); acc = fmaf(bq.y, xs[5], acc);
        acc = fmaf(bq.z, xs[6], acc); acc = fmaf(bq.w, xs[7], acc);
        acc = fmaf(c.x, xs[8], acc);  acc = fmaf(c.y, xs[9], acc);
        acc = fmaf(c.z, xs[10], acc); acc = fmaf(c.w, xs[11], acc);
        acc = fmaf(d.x, xs[12], acc); acc = fmaf(d.y, xs[13], acc);
        acc = fmaf(d.z, xs[14], acc); acc = fmaf(d.w, xs[15], acc);
        if (acc < best) { best = acc; bi = m; }    // strict <: first occurrence
    }
    dps[p] = (float)bi;
}

// ---- fallback pure-VALU path ----
__global__ __launch_bounds__(256) void v2_kernel(const float* __restrict__ verts,
                                                 float* __restrict__ v2, int M) {
    int m = blockIdx.x * 256 + threadIdx.x;
    if (m >= M) return;
    const float4* r = (const float4*)(verts + (size_t)m * D);
    float4 a = r[0], b = r[1], c = r[2], d = r[3];
    v2[m] = ((a.x*a.x + a.y*a.y) + (a.z*a.z + a.w*a.w))
          + ((b.x*b.x + b.y*b.y) + (b.z*b.z + b.w*b.w))
          + ((c.x*c.x + c.y*c.y) + (c.z*c.z + c.w*c.w))
          + ((d.x*d.x + d.y*d.y) + (d.z*d.z + d.w*d.w));
}

__global__ __launch_bounds__(256) void argmin_partial(
    const float* __restrict__ feats, const float* __restrict__ verts,
    const float* __restrict__ v2, float* __restrict__ pval, int* __restrict__ pidx,
    int M, int NPtot, int chunk)
{
    int p = blockIdx.x * 256 + threadIdx.x;
    if (p >= NPtot) return;
    int b = p / NPIX, n = p - b * NPIX;
    const float* xf = feats + ((size_t)b * D) * NPIX + n;
    float x[D];
#pragma unroll
    for (int d2 = 0; d2 < D; ++d2) x[d2] = -2.0f * xf[(size_t)d2 * NPIX];
    int s = blockIdx.y;
    int m0 = s * chunk, m1 = m0 + chunk; if (m1 > M) m1 = M;
    float best = INFINITY; int bi = 0;
    for (int m = m0; m < m1; ++m) {
        const float* vr = verts + (size_t)m * D;
        float acc = v2[m];
#pragma unroll
        for (int d2 = 0; d2 < D; ++d2) acc = fmaf(vr[d2], x[d2], acc);
        if (acc < best) { best = acc; bi = m; }
    }
    pval[(size_t)s * NPtot + p] = best;
    pidx[(size_t)s * NPtot + p] = bi;
}

__global__ __launch_bounds__(256) void reduce_idx(
    const float* __restrict__ pval, const int* __restrict__ pidx,
    float* __restrict__ dps, int S, int NP)
{
    int p = blockIdx.x * 256 + threadIdx.x;
    if (p >= NP) return;
    float bv = pval[p]; int bi = pidx[p];
    for (int s = 1; s < S; ++s) {
        float v = pval[(size_t)s * NP + p];
        int   i = pidx[(size_t)s * NP + p];
        if (v < bv || (v == bv && i < bi)) { bv = v; bi = i; }
    }
    dps[p] = (float)bi;
}

// ---- launch ----
extern "C" void kernel_launch(void* const* d_in, const int* in_sizes, int n_in,
                              void* d_out, int out_size, void* d_ws, size_t ws_size,
                              hipStream_t stream)
{
    const float* feats = (const float*)d_in[0];
    const float* verts = (const float*)d_in[1];
    int M          = in_sizes[1] / D;          // 27554
    int feat_elems = in_sizes[0];              // 401408
    int Bn         = feat_elems / (D * NPIX);  // 2
    int NP         = Bn * NPIX;                // 25088
    float* out = (float*)d_out;

    int PTiles = (NP + 31) >> 5;   // 784
    int Mtiles = (M + 31) >> 5;    // 862

    size_t off = 0;
    auto alloc = [&](size_t sz) { size_t o = off; off = (off + sz + 255) & ~(size_t)255; return o; };
    size_t oBF = alloc((size_t)PTiles * TSB);
    size_t oAF = alloc((size_t)(Mtiles + 4 * TG + 2) * TSA);  // dummy tiles: stage overrun + pad
    size_t oV2 = alloc((size_t)M * 4);
    size_t oKY = alloc((size_t)NP * 8);
    size_t need = off;

    int S = 32;

    if (need <= ws_size) {
        char*  bbuf = (char*)d_ws + oBF;
        char*  abuf = (char*)d_ws + oAF;
        float* v2p  = (float*)((char*)d_ws + oV2);
        u64*   keys = (u64*)((char*)d_ws + oKY);

        int nvb = (Mtiles * 32 + 255) / 256;
        int npb = (PTiles * 32 + 255) / 256;
        int nf4 = feat_elems / 4;
        int ncb = (nf4 + 255) / 256;
        int nkb = (NP + 255) / 256;
        prep_fused<<<dim3(nvb + npb + ncb + nkb), dim3(256), 0, stream>>>(
            verts, feats, abuf, bbuf, v2p, out, keys,
            M, Mtiles, NP, PTiles, nvb, npb, ncb, nf4);

        int chunk = (Mtiles + S - 1) / S;
        dim3 sg((PTiles + 4 * G - 1) / (4 * G), S);
        // V0 = real result; V1/V2 = ablation probes (no memory side effects)
        scan_v<0><<<sg, dim3(256), 0, stream>>>(abuf, bbuf, keys, Mtiles, chunk, NP, PTiles);
        scan_v<1><<<sg, dim3(256), 0, stream>>>(abuf, bbuf, keys, Mtiles, chunk, NP, PTiles);
        scan_v<2><<<sg, dim3(256), 0, stream>>>(abuf, bbuf, keys, Mtiles, chunk, NP, PTiles);

        finalize<<<dim3((NP + 255) / 256), dim3(256), 0, stream>>>(
            keys, feats, verts, v2p, out + feat_elems, NP, M);
    } else {
        hipMemcpyAsync(out, feats, (size_t)feat_elems * sizeof(float),
                       hipMemcpyDeviceToDevice, stream);
        char* ws = (char*)d_ws;
        float* v2 = (float*)ws;
        size_t o2 = (((size_t)M * 4) + 255) & ~(size_t)255;
        int S2 = 16;
        while (S2 > 1 && o2 + (size_t)S2 * NP * 8 > ws_size) S2 >>= 1;
        float* pval = (float*)(ws + o2);
        int*   pidx = (int*)(ws + o2 + (size_t)S2 * NP * 4);
        int chunk = (M + S2 - 1) / S2;
        v2_kernel<<<dim3((M + 255) / 256), dim3(256), 0, stream>>>(verts, v2, M);
        argmin_partial<<<dim3((NP + 255) / 256, S2), dim3(256), 0, stream>>>(
            feats, verts, v2, pval, pidx, M, NP, chunk);
        reduce_idx<<<dim3((NP + 255) / 256), dim3(256), 0, stream>>>(
            pval, pidx, out + feat_elems, S2, NP);
    }
}

// Round 18
// 147.643 us; speedup vs baseline: 1.9244x; 1.9244x over previous
//
#include <hip/hip_runtime.h>
#include <math.h>
#include <float.h>

#define GRIDP 112
#define NPIX (GRIDP * GRIDP)   // 12544
#define D 16
#define TSA 3328               // A-buf bytes/vertex-tile: 3 planes*1024 + v2 128B + pad
#define TSB 3072               // B-buf bytes/pixel-tile:  3 planes*1024
#define G 2                    // pixel tiles per wave
#define TG 2                   // vertex tiles per staged group
#define GRPB (TG * TSA)        // 6656 bytes
#define GRPB_PAD 7168          // staged as 7 x 1024B wave-issues (512B overrun into pad)
#define NISS 7

typedef short s16x8 __attribute__((ext_vector_type(8)));
typedef float f32x16 __attribute__((ext_vector_type(16)));
typedef unsigned int uint32;
typedef unsigned long long u64;
typedef const __attribute__((address_space(1))) uint32* gas_ptr;
typedef __attribute__((address_space(3))) uint32* las_ptr;

__device__ inline unsigned short f2bf(float x) {      // RTNE float->bf16 bits
    unsigned u = __float_as_uint(x);
    u += 0x7fffu + ((u >> 16) & 1u);
    return (unsigned short)(u >> 16);
}
__device__ inline float bf2f(unsigned short b) { return __uint_as_float(((unsigned)b) << 16); }

#define MFMA __builtin_amdgcn_mfma_f32_32x32x16_bf16

// monotone f32 -> u32 map (a<b => map(a)<map(b)); equal floats map equal
__device__ inline unsigned fmap(float f) {
    unsigned b = __float_as_uint(f);
    return (b & 0x80000000u) ? ~b : (b | 0x80000000u);
}

// split one row of 16 floats into 3 bf16 planes, 16B vector stores
__device__ __forceinline__ void split_store_row(const float* x, char* base, int row) {
    unsigned short t0[D], t1[D], t2[D];
#pragma unroll
    for (int e = 0; e < D; ++e) {
        float v = x[e];
        unsigned short a = f2bf(v);  float r1 = v - bf2f(a);
        unsigned short b = f2bf(r1); float r2 = r1 - bf2f(b);
        t0[e] = a; t1[e] = b; t2[e] = f2bf(r2);
    }
#pragma unroll
    for (int h2 = 0; h2 < 2; ++h2) {
        char* p = base + h2 * 512 + row * 16;
        s16x8 v0, v1, v2s;
#pragma unroll
        for (int j = 0; j < 8; ++j) {
            v0[j] = (short)t0[h2 * 8 + j];
            v1[j] = (short)t1[h2 * 8 + j];
            v2s[j] = (short)t2[h2 * 8 + j];
        }
        *(s16x8*)(p)        = v0;
        *(s16x8*)(p + 1024) = v1;
        *(s16x8*)(p + 2048) = v2s;
    }
}

// ---- fused prep: [verts | pixels | feats-copy | key-init] segments ----
__global__ __launch_bounds__(256) void prep_fused(
    const float* __restrict__ verts, const float* __restrict__ feats,
    char* __restrict__ abuf, char* __restrict__ bbuf,
    float* __restrict__ v2p, float* __restrict__ outf, u64* __restrict__ keys,
    int M, int Mtiles, int NP, int PTiles, int nvb, int npb, int ncb, int nf4)
{
    int bx = blockIdx.x;
    if (bx < nvb) {
        int mp = bx * 256 + threadIdx.x;
        if (mp >= Mtiles * 32) return;
        int tile = mp >> 5, row = mp & 31;
        float x[D]; float v2;
        if (mp < M) {
            const float4* r4 = (const float4*)(verts + (size_t)mp * D);
            float4 a = r4[0], b = r4[1], c = r4[2], d = r4[3];
            x[0]=a.x; x[1]=a.y; x[2]=a.z; x[3]=a.w;
            x[4]=b.x; x[5]=b.y; x[6]=b.z; x[7]=b.w;
            x[8]=c.x; x[9]=c.y; x[10]=c.z; x[11]=c.w;
            x[12]=d.x; x[13]=d.y; x[14]=d.z; x[15]=d.w;
            float s = 0.f;
#pragma unroll
            for (int e = 0; e < D; ++e) s = fmaf(x[e], x[e], s);
            v2 = s;
            v2p[mp] = s;
        } else {
#pragma unroll
            for (int e = 0; e < D; ++e) x[e] = 0.f;
            v2 = FLT_MAX;   // pad rows never win
        }
        size_t tb = (size_t)tile * TSA;
        int hv = (row >> 2) & 1, rv = (row & 3) + 4 * (row >> 3);
        *(float*)(abuf + tb + 3072 + hv * 64 + rv * 4) = v2;
        split_store_row(x, abuf + tb, row);
    } else if (bx < nvb + npb) {
        int p = (bx - nvb) * 256 + threadIdx.x;
        if (p >= PTiles * 32) return;
        int tile = p >> 5, colr = p & 31;
        float x[D];
        if (p < NP) {
            int b = p / NPIX, n = p - b * NPIX;
            const float* xf = feats + ((size_t)b * D) * NPIX + n;
#pragma unroll
            for (int e = 0; e < D; ++e) x[e] = -2.0f * xf[(size_t)e * NPIX];
        } else {
#pragma unroll
            for (int e = 0; e < D; ++e) x[e] = 0.f;
        }
        split_store_row(x, bbuf + (size_t)tile * TSB, colr);
    } else if (bx < nvb + npb + ncb) {
        int i = (bx - nvb - npb) * 256 + threadIdx.x;     // float4 index
        if (i < nf4)
            ((float4*)outf)[i] = ((const float4*)feats)[i];
    } else {
        int i = (bx - nvb - npb - ncb) * 256 + threadIdx.x;
        if (i < NP) keys[i] = ~0ull;                      // re-init every launch
    }
}

__device__ inline float mintree16(const f32x16& a) {
    float a0 = fminf(fminf(a[0],  a[1]),  a[2]);   // v_min3 tree
    float a1 = fminf(fminf(a[3],  a[4]),  a[5]);
    float a2 = fminf(fminf(a[6],  a[7]),  a[8]);
    float a3 = fminf(fminf(a[9],  a[10]), a[11]);
    float a4 = fminf(fminf(a[12], a[13]), a[14]);
    float a5 = fminf(fminf(a0, a1), a[15]);
    float a6 = fminf(fminf(a2, a3), a4);
    return fminf(a5, a6);
}

// stage one TG-tile group (7 x 1024B wave-issues incl. 512B pad) into LDS
__device__ __forceinline__ void stage_group(const char* gbase, char* lbase,
                                            int wid, int lane) {
    for (int i = wid; i < NISS; i += 4) {
        __builtin_amdgcn_global_load_lds(
            (gas_ptr)(gbase + i * 1024 + lane * 16),
            (las_ptr)(lbase + i * 1024),
            16, 0, 0);
    }
}

struct AFrag { s16x8 ah, am, al; f32x16 c; };

__device__ __forceinline__ AFrag load_frag(const char* lt, int h, int col) {
    AFrag f;
    f.ah = *(const s16x8*)(lt + (size_t)h * 512 + (size_t)col * 16);
    f.am = *(const s16x8*)(lt + 1024 + (size_t)h * 512 + (size_t)col * 16);
    f.al = *(const s16x8*)(lt + 2048 + (size_t)h * 512 + (size_t)col * 16);
    f.c  = *(const f32x16*)(lt + 3072 + (size_t)h * 64);   // broadcast
    return f;
}

// MFMA-only: 6 split-MFMAs per pixel tile, G independent chains.
__device__ __forceinline__ void chain_mfma(
    const AFrag& f, const s16x8* bh, const s16x8* bm, const s16x8* bl,
    f32x16* acc)
{
#pragma unroll
    for (int g = 0; g < G; ++g) acc[g] = MFMA(f.ah, bh[g], f.c, 0, 0, 0);
#pragma unroll
    for (int g = 0; g < G; ++g) acc[g] = MFMA(f.ah, bm[g], acc[g], 0, 0, 0);
#pragma unroll
    for (int g = 0; g < G; ++g) acc[g] = MFMA(f.am, bh[g], acc[g], 0, 0, 0);
#pragma unroll
    for (int g = 0; g < G; ++g) acc[g] = MFMA(f.ah, bl[g], acc[g], 0, 0, 0);
#pragma unroll
    for (int g = 0; g < G; ++g) acc[g] = MFMA(f.am, bm[g], acc[g], 0, 0, 0);
#pragma unroll
    for (int g = 0; g < G; ++g) acc[g] = MFMA(f.al, bh[g], acc[g], 0, 0, 0);
}

// VALU-only: min-tree + best update for one tile's acc set
__device__ __forceinline__ void tree_upd(
    const f32x16* acc, int mt, float* best, int* btl)
{
#pragma unroll
    for (int g = 0; g < G; ++g) {
        float m = mintree16(acc[g]);
        if (m < best[g]) { btl[g] = mt; best[g] = m; }   // strict <: earliest tile
    }
}

// ---- scan: 4 waves/block, G=2 pixel tiles/wave, LDS-staged A-stream ----
// Convoy-breaking: (a) per-block s_sleep stagger de-phases identical blocks
// so one block's MFMA cluster overlaps another's VALU tree phase;
// (b) s_setprio(1) around the MFMA cluster makes the CU scheduler prefer
// the matrix-issuing wave, sustaining the alternation (T5 pattern).
__global__ __launch_bounds__(256) void mfma_scan(
    const char* __restrict__ abuf, const char* __restrict__ bbuf,
    u64* __restrict__ keys, int Mtiles, int chunk, int NP, int PTiles)
{
    __shared__ __align__(16) char smem[2][GRPB_PAD];
    int lane = threadIdx.x & 63;
    int wid  = threadIdx.x >> 6;
    int col  = lane & 31, h = lane >> 5;
    int ptb  = (blockIdx.x * 4 + wid) * G;      // no early return: barriers below

    // temporal stagger: offset co-resident blocks by ~64..256 cycles
    // (s_sleep immediate must be a compile-time constant -> switch dispatch)
    switch ((blockIdx.x ^ blockIdx.y) & 3) {
        case 1: __builtin_amdgcn_s_sleep(1); break;
        case 2: __builtin_amdgcn_s_sleep(2); break;
        case 3: __builtin_amdgcn_s_sleep(3); break;
        default: break;
    }

    s16x8 bh[G], bm[G], bl[G];
#pragma unroll
    for (int g = 0; g < G; ++g) {
        int pt = ptb + g;
        int ptc = pt < PTiles ? pt : PTiles - 1;
        const char* bb = bbuf + (size_t)ptc * TSB + (size_t)h * 512 + (size_t)col * 16;
        bh[g] = *(const s16x8*)bb;
        bm[g] = *(const s16x8*)(bb + 1024);
        bl[g] = *(const s16x8*)(bb + 2048);
    }

    int mt0 = blockIdx.y * chunk;
    int mt1 = mt0 + chunk; if (mt1 > Mtiles) mt1 = Mtiles;
    int nT   = mt1 - mt0;
    int nGrp = (nT + TG - 1) / TG;

    float best[G]; int btl[G];
#pragma unroll
    for (int g = 0; g < G; ++g) { best[g] = FLT_MAX; btl[g] = mt0; }

    const char* gsrc = abuf + (size_t)mt0 * TSA;

    stage_group(gsrc, smem[0], wid, lane);
    __syncthreads();

    int cur = 0;
    for (int grp = 0; grp < nGrp; ++grp) {
        if (grp + 1 < nGrp)
            stage_group(gsrc + (size_t)(grp + 1) * GRPB, smem[cur ^ 1], wid, lane);

        const char* lb = smem[cur];
        int mtb = mt0 + grp * TG;
        int rem = nT - grp * TG;
        if (rem >= 2) {
            AFrag f0 = load_frag(lb, h, col);
            AFrag f1 = load_frag(lb + TSA, h, col);
            f32x16 a0[G], a1[G];
            __builtin_amdgcn_s_setprio(1);
            chain_mfma(f0, bh, bm, bl, a0);   // 12 MFMAs
            chain_mfma(f1, bh, bm, bl, a1);   // 12 more, independent
            __builtin_amdgcn_s_setprio(0);
            tree_upd(a0, mtb,     best, btl); // VALU cluster
            tree_upd(a1, mtb + 1, best, btl);
        } else {
            AFrag f0 = load_frag(lb, h, col);
            f32x16 a0[G];
            __builtin_amdgcn_s_setprio(1);
            chain_mfma(f0, bh, bm, bl, a0);
            __builtin_amdgcn_s_setprio(0);
            tree_upd(a0, mtb, best, btl);
        }
        __syncthreads();    // drains stage (vmcnt) + protects buffer reuse
        cur ^= 1;
    }

    // merge halves (equal value -> smaller tile), then one atomicMin per pixel
#pragma unroll
    for (int g = 0; g < G; ++g) {
        float o = __shfl_xor(best[g], 32, 64);
        int  ot = __shfl_xor(btl[g], 32, 64);
        if (o < best[g] || (o == best[g] && ot < btl[g])) { best[g] = o; btl[g] = ot; }
    }
    if (lane < 32) {
#pragma unroll
        for (int g = 0; g < G; ++g) {
            int pt = ptb + g;
            int px = pt * 32 + col;
            if (pt < PTiles && px < NP) {
                u64 key = ((u64)fmap(best[g]) << 32) | (unsigned)btl[g];
                atomicMin(&keys[px], key);   // min value, tie -> smaller tile
            }
        }
    }
}

// ---- finalize: unpack winning tile, exact fp32 argmin inside it ----
__global__ __launch_bounds__(256) void finalize(
    const u64* __restrict__ keys,
    const float* __restrict__ feats, const float* __restrict__ verts,
    const float* __restrict__ v2p, float* __restrict__ dps,
    int NP, int M)
{
    int p = blockIdx.x * 256 + threadIdx.x;
    if (p >= NP) return;
    int bt = (int)(unsigned)(keys[p] & 0xffffffffu);
    int b = p / NPIX, n = p - b * NPIX;
    const float* xf = feats + ((size_t)b * D) * NPIX + n;
    float xs[D];
#pragma unroll
    for (int d2 = 0; d2 < D; ++d2) xs[d2] = -2.0f * xf[(size_t)d2 * NPIX];
    int m0 = bt * 32, m1 = m0 + 32; if (m1 > M) m1 = M;
    float best = FLT_MAX; int bi = m0;
    for (int m = m0; m < m1; ++m) {
        const float4* vr = (const float4*)(verts + (size_t)m * D);
        float4 a = vr[0], bq = vr[1], c = vr[2], d = vr[3];
        float acc = v2p[m];
        acc = fmaf(a.x, xs[0], acc);  acc = fmaf(a.y, xs[1], acc);
        acc = fmaf(a.z, xs[2], acc);  acc = fmaf(a.w, xs[3], acc);
        acc = fmaf(bq.x, xs[4], acc); acc = fmaf(bq.y, xs[5], acc);
        acc = fmaf(bq.z, xs[6], acc); acc = fmaf(bq.w, xs[7], acc);
        acc = fmaf(c.x, xs[8], acc);  acc = fmaf(c.y, xs[9], acc);
        acc = fmaf(c.z, xs[10], acc); acc = fmaf(c.w, xs[11], acc);
        acc = fmaf(d.x, xs[12], acc); acc = fmaf(d.y, xs[13], acc);
        acc = fmaf(d.z, xs[14], acc); acc = fmaf(d.w, xs[15], acc);
        if (acc < best) { best = acc; bi = m; }    // strict <: first occurrence
    }
    dps[p] = (float)bi;
}

// ---- fallback pure-VALU path ----
__global__ __launch_bounds__(256) void v2_kernel(const float* __restrict__ verts,
                                                 float* __restrict__ v2, int M) {
    int m = blockIdx.x * 256 + threadIdx.x;
    if (m >= M) return;
    const float4* r = (const float4*)(verts + (size_t)m * D);
    float4 a = r[0], b = r[1], c = r[2], d = r[3];
    v2[m] = ((a.x*a.x + a.y*a.y) + (a.z*a.z + a.w*a.w))
          + ((b.x*b.x + b.y*b.y) + (b.z*b.z + b.w*b.w))
          + ((c.x*c.x + c.y*c.y) + (c.z*c.z + c.w*c.w))
          + ((d.x*d.x + d.y*d.y) + (d.z*d.z + d.w*d.w));
}

__global__ __launch_bounds__(256) void argmin_partial(
    const float* __restrict__ feats, const float* __restrict__ verts,
    const float* __restrict__ v2, float* __restrict__ pval, int* __restrict__ pidx,
    int M, int NPtot, int chunk)
{
    int p = blockIdx.x * 256 + threadIdx.x;
    if (p >= NPtot) return;
    int b = p / NPIX, n = p - b * NPIX;
    const float* xf = feats + ((size_t)b * D) * NPIX + n;
    float x[D];
#pragma unroll
    for (int d2 = 0; d2 < D; ++d2) x[d2] = -2.0f * xf[(size_t)d2 * NPIX];
    int s = blockIdx.y;
    int m0 = s * chunk, m1 = m0 + chunk; if (m1 > M) m1 = M;
    float best = INFINITY; int bi = 0;
    for (int m = m0; m < m1; ++m) {
        const float* vr = verts + (size_t)m * D;
        float acc = v2[m];
#pragma unroll
        for (int d2 = 0; d2 < D; ++d2) acc = fmaf(vr[d2], x[d2], acc);
        if (acc < best) { best = acc; bi = m; }
    }
    pval[(size_t)s * NPtot + p] = best;
    pidx[(size_t)s * NPtot + p] = bi;
}

__global__ __launch_bounds__(256) void reduce_idx(
    const float* __restrict__ pval, const int* __restrict__ pidx,
    float* __restrict__ dps, int S, int NP)
{
    int p = blockIdx.x * 256 + threadIdx.x;
    if (p >= NP) return;
    float bv = pval[p]; int bi = pidx[p];
    for (int s = 1; s < S; ++s) {
        float v = pval[(size_t)s * NP + p];
        int   i = pidx[(size_t)s * NP + p];
        if (v < bv || (v == bv && i < bi)) { bv = v; bi = i; }
    }
    dps[p] = (float)bi;
}

// ---- launch ----
extern "C" void kernel_launch(void* const* d_in, const int* in_sizes, int n_in,
                              void* d_out, int out_size, void* d_ws, size_t ws_size,
                              hipStream_t stream)
{
    const float* feats = (const float*)d_in[0];
    const float* verts = (const float*)d_in[1];
    int M          = in_sizes[1] / D;          // 27554
    int feat_elems = in_sizes[0];              // 401408
    int Bn         = feat_elems / (D * NPIX);  // 2
    int NP         = Bn * NPIX;                // 25088
    float* out = (float*)d_out;

    int PTiles = (NP + 31) >> 5;   // 784
    int Mtiles = (M + 31) >> 5;    // 862

    size_t off = 0;
    auto alloc = [&](size_t sz) { size_t o = off; off = (off + sz + 255) & ~(size_t)255; return o; };
    size_t oBF = alloc((size_t)PTiles * TSB);
    size_t oAF = alloc((size_t)(Mtiles + 4 * TG + 2) * TSA);  // dummy tiles: stage overrun + pad
    size_t oV2 = alloc((size_t)M * 4);
    size_t oKY = alloc((size_t)NP * 8);
    size_t need = off;

    int S = 32;

    if (need <= ws_size) {
        char*  bbuf = (char*)d_ws + oBF;
        char*  abuf = (char*)d_ws + oAF;
        float* v2p  = (float*)((char*)d_ws + oV2);
        u64*   keys = (u64*)((char*)d_ws + oKY);

        int nvb = (Mtiles * 32 + 255) / 256;
        int npb = (PTiles * 32 + 255) / 256;
        int nf4 = feat_elems / 4;
        int ncb = (nf4 + 255) / 256;
        int nkb = (NP + 255) / 256;
        prep_fused<<<dim3(nvb + npb + ncb + nkb), dim3(256), 0, stream>>>(
            verts, feats, abuf, bbuf, v2p, out, keys,
            M, Mtiles, NP, PTiles, nvb, npb, ncb, nf4);

        int chunk = (Mtiles + S - 1) / S;
        mfma_scan<<<dim3((PTiles + 4 * G - 1) / (4 * G), S), dim3(256), 0, stream>>>(
            abuf, bbuf, keys, Mtiles, chunk, NP, PTiles);

        finalize<<<dim3((NP + 255) / 256), dim3(256), 0, stream>>>(
            keys, feats, verts, v2p, out + feat_elems, NP, M);
    } else {
        hipMemcpyAsync(out, feats, (size_t)feat_elems * sizeof(float),
                       hipMemcpyDeviceToDevice, stream);
        char* ws = (char*)d_ws;
        float* v2 = (float*)ws;
        size_t o2 = (((size_t)M * 4) + 255) & ~(size_t)255;
        int S2 = 16;
        while (S2 > 1 && o2 + (size_t)S2 * NP * 8 > ws_size) S2 >>= 1;
        float* pval = (float*)(ws + o2);
        int*   pidx = (int*)(ws + o2 + (size_t)S2 * NP * 4);
        int chunk = (M + S2 - 1) / S2;
        v2_kernel<<<dim3((M + 255) / 256), dim3(256), 0, stream>>>(verts, v2, M);
        argmin_partial<<<dim3((NP + 255) / 256, S2), dim3(256), 0, stream>>>(
            feats, verts, v2, pval, pidx, M, NP, chunk);
        reduce_idx<<<dim3((NP + 255) / 256), dim3(256), 0, stream>>>(
            pval, pidx, out + feat_elems, S2, NP);
    }
}

// Round 19
// 140.313 us; speedup vs baseline: 2.0249x; 1.0522x over previous
//
#include <hip/hip_runtime.h>
#include <math.h>
#include <float.h>

#define GRIDP 112
#define NPIX (GRIDP * GRIDP)   // 12544
#define D 16
#define TSA 3328               // A-buf bytes/vertex-tile: 3 planes*1024 + v2 128B + pad
#define TSB 3072               // B-buf bytes/pixel-tile:  3 planes*1024
#define G 2                    // pixel tiles per wave
#define CHUNK 14               // vertex tiles per block (S=64 chunks over 862 tiles)
#define LDSB 47104             // 46 x 1024B stage issues (>= CHUNK*TSA = 46592)
#define NISS 46

typedef short s16x8 __attribute__((ext_vector_type(8)));
typedef float f32x16 __attribute__((ext_vector_type(16)));
typedef unsigned int uint32;
typedef unsigned long long u64;
typedef const __attribute__((address_space(1))) uint32* gas_ptr;
typedef __attribute__((address_space(3))) uint32* las_ptr;

__device__ inline unsigned short f2bf(float x) {      // RTNE float->bf16 bits
    unsigned u = __float_as_uint(x);
    u += 0x7fffu + ((u >> 16) & 1u);
    return (unsigned short)(u >> 16);
}
__device__ inline float bf2f(unsigned short b) { return __uint_as_float(((unsigned)b) << 16); }

#define MFMA __builtin_amdgcn_mfma_f32_32x32x16_bf16

// monotone f32 -> u32 map (a<b => map(a)<map(b)); equal floats map equal
__device__ inline unsigned fmap(float f) {
    unsigned b = __float_as_uint(f);
    return (b & 0x80000000u) ? ~b : (b | 0x80000000u);
}

// split one row of 16 floats into 3 bf16 planes, 16B vector stores
__device__ __forceinline__ void split_store_row(const float* x, char* base, int row) {
    unsigned short t0[D], t1[D], t2[D];
#pragma unroll
    for (int e = 0; e < D; ++e) {
        float v = x[e];
        unsigned short a = f2bf(v);  float r1 = v - bf2f(a);
        unsigned short b = f2bf(r1); float r2 = r1 - bf2f(b);
        t0[e] = a; t1[e] = b; t2[e] = f2bf(r2);
    }
#pragma unroll
    for (int h2 = 0; h2 < 2; ++h2) {
        char* p = base + h2 * 512 + row * 16;
        s16x8 v0, v1, v2s;
#pragma unroll
        for (int j = 0; j < 8; ++j) {
            v0[j] = (short)t0[h2 * 8 + j];
            v1[j] = (short)t1[h2 * 8 + j];
            v2s[j] = (short)t2[h2 * 8 + j];
        }
        *(s16x8*)(p)        = v0;
        *(s16x8*)(p + 1024) = v1;
        *(s16x8*)(p + 2048) = v2s;
    }
}

// ---- fused prep: [verts | pixels | feats-copy | key-init] segments ----
__global__ __launch_bounds__(256) void prep_fused(
    const float* __restrict__ verts, const float* __restrict__ feats,
    char* __restrict__ abuf, char* __restrict__ bbuf,
    float* __restrict__ v2p, float* __restrict__ outf, u64* __restrict__ keys,
    int M, int Mtiles, int NP, int PTiles, int nvb, int npb, int ncb, int nf4)
{
    int bx = blockIdx.x;
    if (bx < nvb) {
        int mp = bx * 256 + threadIdx.x;
        if (mp >= Mtiles * 32) return;
        int tile = mp >> 5, row = mp & 31;
        float x[D]; float v2;
        if (mp < M) {
            const float4* r4 = (const float4*)(verts + (size_t)mp * D);
            float4 a = r4[0], b = r4[1], c = r4[2], d = r4[3];
            x[0]=a.x; x[1]=a.y; x[2]=a.z; x[3]=a.w;
            x[4]=b.x; x[5]=b.y; x[6]=b.z; x[7]=b.w;
            x[8]=c.x; x[9]=c.y; x[10]=c.z; x[11]=c.w;
            x[12]=d.x; x[13]=d.y; x[14]=d.z; x[15]=d.w;
            float s = 0.f;
#pragma unroll
            for (int e = 0; e < D; ++e) s = fmaf(x[e], x[e], s);
            v2 = s;
            v2p[mp] = s;
        } else {
#pragma unroll
            for (int e = 0; e < D; ++e) x[e] = 0.f;
            v2 = FLT_MAX;   // pad rows never win
        }
        size_t tb = (size_t)tile * TSA;
        int hv = (row >> 2) & 1, rv = (row & 3) + 4 * (row >> 3);
        *(float*)(abuf + tb + 3072 + hv * 64 + rv * 4) = v2;
        split_store_row(x, abuf + tb, row);
    } else if (bx < nvb + npb) {
        int p = (bx - nvb) * 256 + threadIdx.x;
        if (p >= PTiles * 32) return;
        int tile = p >> 5, colr = p & 31;
        float x[D];
        if (p < NP) {
            int b = p / NPIX, n = p - b * NPIX;
            const float* xf = feats + ((size_t)b * D) * NPIX + n;
#pragma unroll
            for (int e = 0; e < D; ++e) x[e] = -2.0f * xf[(size_t)e * NPIX];
        } else {
#pragma unroll
            for (int e = 0; e < D; ++e) x[e] = 0.f;
        }
        split_store_row(x, bbuf + (size_t)tile * TSB, colr);
    } else if (bx < nvb + npb + ncb) {
        int i = (bx - nvb - npb) * 256 + threadIdx.x;     // float4 index
        if (i < nf4)
            ((float4*)outf)[i] = ((const float4*)feats)[i];
    } else {
        int i = (bx - nvb - npb - ncb) * 256 + threadIdx.x;
        if (i < NP) keys[i] = ~0ull;                      // re-init every launch
    }
}

__device__ inline float mintree16(const f32x16& a) {
    float a0 = fminf(fminf(a[0],  a[1]),  a[2]);   // v_min3 tree
    float a1 = fminf(fminf(a[3],  a[4]),  a[5]);
    float a2 = fminf(fminf(a[6],  a[7]),  a[8]);
    float a3 = fminf(fminf(a[9],  a[10]), a[11]);
    float a4 = fminf(fminf(a[12], a[13]), a[14]);
    float a5 = fminf(fminf(a0, a1), a[15]);
    float a6 = fminf(fminf(a2, a3), a4);
    return fminf(a5, a6);
}

struct AFrag { s16x8 ah, am, al; f32x16 c; };

__device__ __forceinline__ AFrag load_frag(const char* lt, int h, int col) {
    AFrag f;
    f.ah = *(const s16x8*)(lt + (size_t)h * 512 + (size_t)col * 16);
    f.am = *(const s16x8*)(lt + 1024 + (size_t)h * 512 + (size_t)col * 16);
    f.al = *(const s16x8*)(lt + 2048 + (size_t)h * 512 + (size_t)col * 16);
    f.c  = *(const f32x16*)(lt + 3072 + (size_t)h * 64);   // broadcast
    return f;
}

// MFMA-only: 6 split-MFMAs per pixel tile, G independent chains.
__device__ __forceinline__ void chain_mfma(
    const AFrag& f, const s16x8* bh, const s16x8* bm, const s16x8* bl,
    f32x16* acc)
{
#pragma unroll
    for (int g = 0; g < G; ++g) acc[g] = MFMA(f.ah, bh[g], f.c, 0, 0, 0);
#pragma unroll
    for (int g = 0; g < G; ++g) acc[g] = MFMA(f.ah, bm[g], acc[g], 0, 0, 0);
#pragma unroll
    for (int g = 0; g < G; ++g) acc[g] = MFMA(f.am, bh[g], acc[g], 0, 0, 0);
#pragma unroll
    for (int g = 0; g < G; ++g) acc[g] = MFMA(f.ah, bl[g], acc[g], 0, 0, 0);
#pragma unroll
    for (int g = 0; g < G; ++g) acc[g] = MFMA(f.am, bm[g], acc[g], 0, 0, 0);
#pragma unroll
    for (int g = 0; g < G; ++g) acc[g] = MFMA(f.al, bh[g], acc[g], 0, 0, 0);
}

// VALU-only: min-tree + best update for one tile's acc set
__device__ __forceinline__ void tree_upd(
    const f32x16* acc, int mt, float* best, int* btl)
{
#pragma unroll
    for (int g = 0; g < G; ++g) {
        float m = mintree16(acc[g]);
        if (m < best[g]) { btl[g] = mt; best[g] = m; }   // strict <: earliest tile
    }
}

// ---- scan: single-shot staged chunk (CHUNK=14 tiles), ONE barrier total ----
// After the initial stage+barrier, waves free-run with no synchronization:
// they de-phase naturally, so one wave's MFMA queue executes under another
// wave's tree-latency window (the overlap per-group barriers prevented).
__global__ __launch_bounds__(256) void mfma_scan(
    const char* __restrict__ abuf, const char* __restrict__ bbuf,
    u64* __restrict__ keys, int Mtiles, int chunk, int NP, int PTiles)
{
    __shared__ __align__(16) char smem[LDSB];
    int lane = threadIdx.x & 63;
    int wid  = threadIdx.x >> 6;
    int col  = lane & 31, h = lane >> 5;
    int ptb  = (blockIdx.x * 4 + wid) * G;

    s16x8 bh[G], bm[G], bl[G];
#pragma unroll
    for (int g = 0; g < G; ++g) {
        int pt = ptb + g;
        int ptc = pt < PTiles ? pt : PTiles - 1;
        const char* bb = bbuf + (size_t)ptc * TSB + (size_t)h * 512 + (size_t)col * 16;
        bh[g] = *(const s16x8*)bb;
        bm[g] = *(const s16x8*)(bb + 1024);
        bl[g] = *(const s16x8*)(bb + 2048);
    }

    int mt0 = blockIdx.y * chunk;
    int mt1 = mt0 + chunk; if (mt1 > Mtiles) mt1 = Mtiles;
    int nT  = mt1 - mt0;                 // may be <= 0 for tail blocks

    // stage the whole chunk (46 x 1024B issues; source has dummy-tile pad)
    const char* gsrc = abuf + (size_t)mt0 * TSA;
    for (int i = wid; i < NISS; i += 4) {
        __builtin_amdgcn_global_load_lds(
            (gas_ptr)(gsrc + i * 1024 + lane * 16),
            (las_ptr)(smem + i * 1024),
            16, 0, 0);
    }
    __syncthreads();                     // the ONLY barrier

    float best[G]; int btl[G];
#pragma unroll
    for (int g = 0; g < G; ++g) { best[g] = FLT_MAX; btl[g] = mt0; }

    int t = 0;
    for (; t + 1 < nT; t += 2) {         // pairs: 24 MFMAs issued before trees
        AFrag f0 = load_frag(smem + (size_t)t * TSA,       h, col);
        AFrag f1 = load_frag(smem + (size_t)(t + 1) * TSA, h, col);
        f32x16 a0[G], a1[G];
        chain_mfma(f0, bh, bm, bl, a0);
        chain_mfma(f1, bh, bm, bl, a1);
        tree_upd(a0, mt0 + t,     best, btl);
        tree_upd(a1, mt0 + t + 1, best, btl);
    }
    if (t < nT) {
        AFrag f0 = load_frag(smem + (size_t)t * TSA, h, col);
        f32x16 a0[G];
        chain_mfma(f0, bh, bm, bl, a0);
        tree_upd(a0, mt0 + t, best, btl);
    }

    if (nT <= 0) return;                 // tail chunk past Mtiles: nothing to report

    // merge halves (equal value -> smaller tile), then one atomicMin per pixel
#pragma unroll
    for (int g = 0; g < G; ++g) {
        float o = __shfl_xor(best[g], 32, 64);
        int  ot = __shfl_xor(btl[g], 32, 64);
        if (o < best[g] || (o == best[g] && ot < btl[g])) { best[g] = o; btl[g] = ot; }
    }
    if (lane < 32) {
#pragma unroll
        for (int g = 0; g < G; ++g) {
            int pt = ptb + g;
            int px = pt * 32 + col;
            if (pt < PTiles && px < NP) {
                u64 key = ((u64)fmap(best[g]) << 32) | (unsigned)btl[g];
                atomicMin(&keys[px], key);   // min value, tie -> smaller tile
            }
        }
    }
}

// ---- finalize: unpack winning tile, exact fp32 argmin inside it ----
__global__ __launch_bounds__(256) void finalize(
    const u64* __restrict__ keys,
    const float* __restrict__ feats, const float* __restrict__ verts,
    const float* __restrict__ v2p, float* __restrict__ dps,
    int NP, int M)
{
    int p = blockIdx.x * 256 + threadIdx.x;
    if (p >= NP) return;
    int bt = (int)(unsigned)(keys[p] & 0xffffffffu);
    int b = p / NPIX, n = p - b * NPIX;
    const float* xf = feats + ((size_t)b * D) * NPIX + n;
    float xs[D];
#pragma unroll
    for (int d2 = 0; d2 < D; ++d2) xs[d2] = -2.0f * xf[(size_t)d2 * NPIX];
    int m0 = bt * 32, m1 = m0 + 32; if (m1 > M) m1 = M;
    float best = FLT_MAX; int bi = m0;
    for (int m = m0; m < m1; ++m) {
        const float4* vr = (const float4*)(verts + (size_t)m * D);
        float4 a = vr[0], bq = vr[1], c = vr[2], d = vr[3];
        float acc = v2p[m];
        acc = fmaf(a.x, xs[0], acc);  acc = fmaf(a.y, xs[1], acc);
        acc = fmaf(a.z, xs[2], acc);  acc = fmaf(a.w, xs[3], acc);
        acc = fmaf(bq.x, xs[4], acc); acc = fmaf(bq.y, xs[5], acc);
        acc = fmaf(bq.z, xs[6], acc); acc = fmaf(bq.w, xs[7], acc);
        acc = fmaf(c.x, xs[8], acc);  acc = fmaf(c.y, xs[9], acc);
        acc = fmaf(c.z, xs[10], acc); acc = fmaf(c.w, xs[11], acc);
        acc = fmaf(d.x, xs[12], acc); acc = fmaf(d.y, xs[13], acc);
        acc = fmaf(d.z, xs[14], acc); acc = fmaf(d.w, xs[15], acc);
        if (acc < best) { best = acc; bi = m; }    // strict <: first occurrence
    }
    dps[p] = (float)bi;
}

// ---- fallback pure-VALU path ----
__global__ __launch_bounds__(256) void v2_kernel(const float* __restrict__ verts,
                                                 float* __restrict__ v2, int M) {
    int m = blockIdx.x * 256 + threadIdx.x;
    if (m >= M) return;
    const float4* r = (const float4*)(verts + (size_t)m * D);
    float4 a = r[0], b = r[1], c = r[2], d = r[3];
    v2[m] = ((a.x*a.x + a.y*a.y) + (a.z*a.z + a.w*a.w))
          + ((b.x*b.x + b.y*b.y) + (b.z*b.z + b.w*b.w))
          + ((c.x*c.x + c.y*c.y) + (c.z*c.z + c.w*c.w))
          + ((d.x*d.x + d.y*d.y) + (d.z*d.z + d.w*d.w));
}

__global__ __launch_bounds__(256) void argmin_partial(
    const float* __restrict__ feats, const float* __restrict__ verts,
    const float* __restrict__ v2, float* __restrict__ pval, int* __restrict__ pidx,
    int M, int NPtot, int chunk)
{
    int p = blockIdx.x * 256 + threadIdx.x;
    if (p >= NPtot) return;
    int b = p / NPIX, n = p - b * NPIX;
    const float* xf = feats + ((size_t)b * D) * NPIX + n;
    float x[D];
#pragma unroll
    for (int d2 = 0; d2 < D; ++d2) x[d2] = -2.0f * xf[(size_t)d2 * NPIX];
    int s = blockIdx.y;
    int m0 = s * chunk, m1 = m0 + chunk; if (m1 > M) m1 = M;
    float best = INFINITY; int bi = 0;
    for (int m = m0; m < m1; ++m) {
        const float* vr = verts + (size_t)m * D;
        float acc = v2[m];
#pragma unroll
        for (int d2 = 0; d2 < D; ++d2) acc = fmaf(vr[d2], x[d2], acc);
        if (acc < best) { best = acc; bi = m; }
    }
    pval[(size_t)s * NPtot + p] = best;
    pidx[(size_t)s * NPtot + p] = bi;
}

__global__ __launch_bounds__(256) void reduce_idx(
    const float* __restrict__ pval, const int* __restrict__ pidx,
    float* __restrict__ dps, int S, int NP)
{
    int p = blockIdx.x * 256 + threadIdx.x;
    if (p >= NP) return;
    float bv = pval[p]; int bi = pidx[p];
    for (int s = 1; s < S; ++s) {
        float v = pval[(size_t)s * NP + p];
        int   i = pidx[(size_t)s * NP + p];
        if (v < bv || (v == bv && i < bi)) { bv = v; bi = i; }
    }
    dps[p] = (float)bi;
}

// ---- launch ----
extern "C" void kernel_launch(void* const* d_in, const int* in_sizes, int n_in,
                              void* d_out, int out_size, void* d_ws, size_t ws_size,
                              hipStream_t stream)
{
    const float* feats = (const float*)d_in[0];
    const float* verts = (const float*)d_in[1];
    int M          = in_sizes[1] / D;          // 27554
    int feat_elems = in_sizes[0];              // 401408
    int Bn         = feat_elems / (D * NPIX);  // 2
    int NP         = Bn * NPIX;                // 25088
    float* out = (float*)d_out;

    int PTiles = (NP + 31) >> 5;   // 784
    int Mtiles = (M + 31) >> 5;    // 862

    int S = 64;
    int chunk = (Mtiles + S - 1) / S;          // 14
    int atiles = S * chunk + 16;               // stage-overrun dummy pad

    size_t off = 0;
    auto alloc = [&](size_t sz) { size_t o = off; off = (off + sz + 255) & ~(size_t)255; return o; };
    size_t oBF = alloc((size_t)PTiles * TSB);
    size_t oAF = alloc((size_t)atiles * TSA);
    size_t oV2 = alloc((size_t)M * 4);
    size_t oKY = alloc((size_t)NP * 8);
    size_t need = off;

    if (need <= ws_size && chunk <= CHUNK) {
        char*  bbuf = (char*)d_ws + oBF;
        char*  abuf = (char*)d_ws + oAF;
        float* v2p  = (float*)((char*)d_ws + oV2);
        u64*   keys = (u64*)((char*)d_ws + oKY);

        int nvb = (Mtiles * 32 + 255) / 256;
        int npb = (PTiles * 32 + 255) / 256;
        int nf4 = feat_elems / 4;
        int ncb = (nf4 + 255) / 256;
        int nkb = (NP + 255) / 256;
        prep_fused<<<dim3(nvb + npb + ncb + nkb), dim3(256), 0, stream>>>(
            verts, feats, abuf, bbuf, v2p, out, keys,
            M, Mtiles, NP, PTiles, nvb, npb, ncb, nf4);

        mfma_scan<<<dim3((PTiles + 4 * G - 1) / (4 * G), S), dim3(256), 0, stream>>>(
            abuf, bbuf, keys, Mtiles, chunk, NP, PTiles);

        finalize<<<dim3((NP + 255) / 256), dim3(256), 0, stream>>>(
            keys, feats, verts, v2p, out + feat_elems, NP, M);
    } else {
        hipMemcpyAsync(out, feats, (size_t)feat_elems * sizeof(float),
                       hipMemcpyDeviceToDevice, stream);
        char* ws = (char*)d_ws;
        float* v2 = (float*)ws;
        size_t o2 = (((size_t)M * 4) + 255) & ~(size_t)255;
        int S2 = 16;
        while (S2 > 1 && o2 + (size_t)S2 * NP * 8 > ws_size) S2 >>= 1;
        float* pval = (float*)(ws + o2);
        int*   pidx = (int*)(ws + o2 + (size_t)S2 * NP * 4);
        int chunk2 = (M + S2 - 1) / S2;
        v2_kernel<<<dim3((M + 255) / 256), dim3(256), 0, stream>>>(verts, v2, M);
        argmin_partial<<<dim3((NP + 255) / 256, S2), dim3(256), 0, stream>>>(
            feats, verts, v2, pval, pidx, M, NP, chunk2);
        reduce_idx<<<dim3((NP + 255) / 256), dim3(256), 0, stream>>>(
            pval, pidx, out + feat_elems, S2, NP);
    }
}